// Round 1
// baseline (148.325 us; speedup 1.0000x reference)
//
#include <hip/hip_runtime.h>
#include <stdint.h>

// Problem constants (from reference: B=2048, D=512, TAU=0.5)
#define DIM       512
#define NROWS     8192      // 4*B
#define HALF_ROWS 4096      // 2*B
#define TILE      128
#define BK        32

typedef float  floatx4 __attribute__((ext_vector_type(4)));
typedef __bf16 bf16x8  __attribute__((ext_vector_type(8)));

__device__ __forceinline__ void async_copy16(const unsigned short* g, unsigned short* l) {
    __builtin_amdgcn_global_load_lds(
        (const __attribute__((address_space(1))) uint32_t*)(g),
        (__attribute__((address_space(3))) uint32_t*)(l),
        16, 0, 0);
}

__global__ void init_ws(double* ws) {
    ws[0] = 0.0;  // sum over all ordered off-diagonal pairs of exp(sim/tau)
    ws[1] = 0.0;  // nominator: sum over |i-j| in {B,2B,3B}
}

// L2-normalize rows of [emb_i; emb_j] and store as bf16 into rep[8192][512].
// 4 rows per block (one per wave); lane handles 8 consecutive floats.
__global__ __launch_bounds__(256) void normalize_kernel(
    const float* __restrict__ emb_i, const float* __restrict__ emb_j,
    unsigned short* __restrict__ rep)
{
    const int wave = threadIdx.x >> 6;
    const int lane = threadIdx.x & 63;
    const int row  = blockIdx.x * 4 + wave;
    const float* src = (row < HALF_ROWS) ? (emb_i + (size_t)row * DIM)
                                         : (emb_j + (size_t)(row - HALF_ROWS) * DIM);
    const int c = lane * 8;
    float4 v0 = *(const float4*)(src + c);
    float4 v1 = *(const float4*)(src + c + 4);
    float s = v0.x*v0.x + v0.y*v0.y + v0.z*v0.z + v0.w*v0.w
            + v1.x*v1.x + v1.y*v1.y + v1.z*v1.z + v1.w*v1.w;
    #pragma unroll
    for (int off = 32; off; off >>= 1) s += __shfl_xor(s, off, 64);
    const float nrm = sqrtf(s);
    const float inv = 1.0f / fmaxf(nrm, 1e-12f);
    float f[8] = {v0.x*inv, v0.y*inv, v0.z*inv, v0.w*inv,
                  v1.x*inv, v1.y*inv, v1.z*inv, v1.w*inv};
    union { unsigned short h[8]; uint4 u; } pk;
    #pragma unroll
    for (int t = 0; t < 8; ++t) {   // fp32 -> bf16 round-to-nearest-even
        uint32_t b = __float_as_uint(f[t]);
        b += 0x7FFFu + ((b >> 16) & 1u);
        pk.h[t] = (unsigned short)(b >> 16);
    }
    *(uint4*)(rep + (size_t)row * DIM + c) = pk.u;
}

// Fused Gram-tile + exp + reduction. Upper-triangle tiles only (bj >= bi),
// off-diagonal tiles weighted x2 (covers the transpose half).
__global__ __launch_bounds__(256) void gram_kernel(
    const unsigned short* __restrict__ rep, double* __restrict__ ws)
{
    const int bj = blockIdx.x, bi = blockIdx.y;
    if (bj < bi) return;

    __shared__ unsigned short As[TILE * BK];   // 8 KB, row-major [128][32]
    __shared__ unsigned short Bs[TILE * BK];   // 8 KB
    __shared__ float red[8];

    const int tid  = threadIdx.x;
    const int wave = tid >> 6, lane = tid & 63;
    const int wm = wave >> 1, wn = wave & 1;   // 2x2 waves of 64x64 quadrants
    const int m = lane & 15, quad = lane >> 4; // MFMA fragment coords

    floatx4 acc[4][4];
    #pragma unroll
    for (int a = 0; a < 4; ++a)
        #pragma unroll
        for (int b = 0; b < 4; ++b)
            #pragma unroll
            for (int e = 0; e < 4; ++e) acc[a][b][e] = 0.0f;

    const int i0 = bi * TILE, j0 = bj * TILE;

    for (int k0 = 0; k0 < DIM; k0 += BK) {
        // Stage A (rows i0..i0+127) and B (rows j0..j0+127), 32 cols each,
        // into LDS via direct global->LDS DMA (16 B per lane, lane-contiguous).
        #pragma unroll
        for (int r = 0; r < 2; ++r) {
            const int chunk = r * 256 + tid;          // 512 chunks of 16 B
            const int row   = chunk >> 2;             // 4 chunks per 32-col row
            const int cc    = (chunk & 3) * 8;
            async_copy16(rep + (size_t)(i0 + row) * DIM + k0 + cc, As + chunk * 8);
            async_copy16(rep + (size_t)(j0 + row) * DIM + k0 + cc, Bs + chunk * 8);
        }
        __syncthreads();

        bf16x8 af[4], bfr[4];
        #pragma unroll
        for (int mt = 0; mt < 4; ++mt)
            af[mt] = *(const bf16x8*)(As + (wm * 64 + mt * 16 + m) * BK + quad * 8);
        #pragma unroll
        for (int nt = 0; nt < 4; ++nt)
            bfr[nt] = *(const bf16x8*)(Bs + (wn * 64 + nt * 16 + m) * BK + quad * 8);
        #pragma unroll
        for (int mt = 0; mt < 4; ++mt)
            #pragma unroll
            for (int nt = 0; nt < 4; ++nt)
                acc[mt][nt] = __builtin_amdgcn_mfma_f32_16x16x32_bf16(
                    af[mt], bfr[nt], acc[mt][nt], 0, 0, 0);
        __syncthreads();
    }

    // Epilogue: exp(sim/tau) = exp2(sim * 2/ln2); accumulate total + band sums.
    float s_all = 0.0f, s_pos = 0.0f;
    const float LOG2E2 = 2.885390081777927f;  // 2 / ln(2)
    #pragma unroll
    for (int mt = 0; mt < 4; ++mt) {
        const int ibase = i0 + wm * 64 + mt * 16 + quad * 4;
        #pragma unroll
        for (int nt = 0; nt < 4; ++nt) {
            const int j = j0 + wn * 64 + nt * 16 + m;
            const floatx4 a = acc[mt][nt];
            #pragma unroll
            for (int r2 = 0; r2 < 4; ++r2) {
                const int i = ibase + r2;
                const float e = exp2f(a[r2] * LOG2E2);
                if (i != j) s_all += e;
                const int d = j - i;  // upper triangle: band offsets positive
                if (d == 2048 || d == 4096 || d == 6144) s_pos += e;
            }
        }
    }
    #pragma unroll
    for (int off = 32; off; off >>= 1) {
        s_all += __shfl_xor(s_all, off, 64);
        s_pos += __shfl_xor(s_pos, off, 64);
    }
    if (lane == 0) { red[wave] = s_all; red[4 + wave] = s_pos; }
    __syncthreads();
    if (tid == 0) {
        const float w  = (bi == bj) ? 1.0f : 2.0f;
        const float ta = (red[0] + red[1] + red[2] + red[3]) * w;
        const float tp = (red[4] + red[5] + red[6] + red[7]) * w;
        atomicAdd(&ws[0], (double)ta);
        atomicAdd(&ws[1], (double)tp);
    }
}

__global__ void finalize_kernel(const double* __restrict__ ws, float* __restrict__ out) {
    const double nom = ws[1];
    const double den = ws[0] - nom;
    out[0] = (float)(-log(nom / den) / (double)NROWS);
}

extern "C" void kernel_launch(void* const* d_in, const int* in_sizes, int n_in,
                              void* d_out, int out_size, void* d_ws, size_t ws_size,
                              hipStream_t stream) {
    const float* emb_i = (const float*)d_in[0];
    const float* emb_j = (const float*)d_in[1];
    float* out = (float*)d_out;
    double* ws = (double*)d_ws;                                   // 2 accumulators
    unsigned short* rep = (unsigned short*)((char*)d_ws + 256);   // bf16 [8192][512]

    hipLaunchKernelGGL(init_ws, dim3(1), dim3(1), 0, stream, ws);
    hipLaunchKernelGGL(normalize_kernel, dim3(NROWS / 4), dim3(256), 0, stream,
                       emb_i, emb_j, rep);
    hipLaunchKernelGGL(gram_kernel, dim3(64, 64), dim3(256), 0, stream, rep, ws);
    hipLaunchKernelGGL(finalize_kernel, dim3(1), dim3(1), 0, stream, ws, out);
}